// Round 9
// baseline (460.468 us; speedup 1.0000x reference)
//
#include <hip/hip_runtime.h>
#include <math.h>

#define BB 32
#define CC 2048
#define NN 784          // 28*28
#define NF4 196         // float4 per (b,c) spatial row
#define MM 4
#define NCH 128         // channel chunks (CPER=16 per wave)
#define CPER (CC / NCH)
#define LAMBDA_ 1e-3f
#define EPS_ 1e-10f
#define LOG1E4 9.210340371976184f
#define OUT_BLOCKS (BB * CC / 4)    // 16384

__device__ __forceinline__ float wred(float v) {
#pragma unroll
  for (int off = 32; off > 0; off >>= 1) v += __shfl_down(v, off, 64);
  return v;
}

// ---- K1: fused norm + partial dot. Wave-private (no LDS/barriers).
//          4 channels per step: 4 interleaved butterflies (4-way ILP on the
//          shfl chain), double-batch ping-pong, fully static indexing.
//          peW side-blocks at blockIdx.x == NCH/4. NO launch_bounds cap:
//          R6 proved capping below ~220 VGPR rematerializes and serializes. ----
__global__ void k_sacc2v2(const float* __restrict__ x,
                          const float* __restrict__ W,
                          float* __restrict__ inv_norm,
                          float* __restrict__ peW,
                          float4* __restrict__ sPart4) {
  int b    = blockIdx.y;
  int wv   = threadIdx.x >> 6;
  int lane = threadIdx.x & 63;

  if (blockIdx.x == NCH / 4) {
    // peW[m,n] = sum_c pe[n,c]*W[m,c]; 25-wide n slice per b.
    const int NPS = (NN + BB - 1) / BB;   // 25
    int n0 = b * NPS, n1 = (n0 + NPS < NN) ? n0 + NPS : NN;
    int m = wv;
    for (int n = n0; n < n1; ++n) {
      float acc = 0.f;
      for (int c = lane; c < CC; c += 64) {
        float di  = __expf(-((float)(c & ~1) * (1.f / CC)) * LOG1E4);
        float arg = (float)n * di;
        float pe  = (c & 1) ? __cosf(arg) : __sinf(arg);
        acc += pe * W[m * CC + c];
      }
      acc = wred(acc);
      if (lane == 0) peW[m * NN + n] = acc;
    }
    return;
  }

  int ch = blockIdx.x * 4 + wv;
  int c0 = ch * CPER;
  const float4* xb = (const float4*)(x + ((size_t)b * CC + c0) * NN);
  const float4 z = make_float4(0.f, 0.f, 0.f, 0.f);

  float4 acc[MM][4];
#pragma unroll
  for (int m = 0; m < MM; ++m)
#pragma unroll
    for (int j = 0; j < 4; ++j) acc[m][j] = z;

  float4 xA[4][4], xB[4][4];   // [channel-in-batch][slot]

  auto LOADB = [&](float4 d[4][4], int bt) {   // load 4 channels of batch bt
#pragma unroll
    for (int k = 0; k < 4; ++k) {
      const float4* p = xb + (size_t)(bt * 4 + k) * NF4 + lane;
      d[k][0] = p[0];
      d[k][1] = p[64];
      d[k][2] = p[128];
      d[k][3] = (lane < (NF4 - 192)) ? p[192] : z;
    }
  };

  auto COMPB = [&](const float4 v[4][4], int bt) {
    int cb = c0 + bt * 4;
    // weight broadcast loads (independent of inv; issue early)
    float wl[4][MM];
#pragma unroll
    for (int k = 0; k < 4; ++k)
#pragma unroll
      for (int m = 0; m < MM; ++m) wl[k][m] = W[m * CC + cb + k];
    // 4 sumsq chains
    float sq[4];
#pragma unroll
    for (int k = 0; k < 4; ++k) {
      sq[k] = v[k][0].x*v[k][0].x + v[k][0].y*v[k][0].y + v[k][0].z*v[k][0].z + v[k][0].w*v[k][0].w
            + v[k][1].x*v[k][1].x + v[k][1].y*v[k][1].y + v[k][1].z*v[k][1].z + v[k][1].w*v[k][1].w
            + v[k][2].x*v[k][2].x + v[k][2].y*v[k][2].y + v[k][2].z*v[k][2].z + v[k][2].w*v[k][2].w
            + v[k][3].x*v[k][3].x + v[k][3].y*v[k][3].y + v[k][3].z*v[k][3].z + v[k][3].w*v[k][3].w;
    }
    // interleaved butterflies: 4 independent chains per level
#pragma unroll
    for (int o = 1; o < 64; o <<= 1) {
      sq[0] += __shfl_xor(sq[0], o, 64);
      sq[1] += __shfl_xor(sq[1], o, 64);
      sq[2] += __shfl_xor(sq[2], o, 64);
      sq[3] += __shfl_xor(sq[3], o, 64);
    }
    float inv[4];
#pragma unroll
    for (int k = 0; k < 4; ++k) inv[k] = 1.f / fmaxf(sqrtf(sq[k]), EPS_);
    if (lane == 0) {
#pragma unroll
      for (int k = 0; k < 4; ++k) inv_norm[b * CC + cb + k] = inv[k];
    }
#pragma unroll
    for (int k = 0; k < 4; ++k) {
      float w0 = inv[k] * wl[k][0];
      float w1 = inv[k] * wl[k][1];
      float w2 = inv[k] * wl[k][2];
      float w3 = inv[k] * wl[k][3];
#pragma unroll
      for (int j = 0; j < 4; ++j) {
        float4 v4 = v[k][j];
        acc[0][j].x += v4.x * w0; acc[0][j].y += v4.y * w0; acc[0][j].z += v4.z * w0; acc[0][j].w += v4.w * w0;
        acc[1][j].x += v4.x * w1; acc[1][j].y += v4.y * w1; acc[1][j].z += v4.z * w1; acc[1][j].w += v4.w * w1;
        acc[2][j].x += v4.x * w2; acc[2][j].y += v4.y * w2; acc[2][j].z += v4.z * w2; acc[2][j].w += v4.w * w2;
        acc[3][j].x += v4.x * w3; acc[3][j].y += v4.y * w3; acc[3][j].z += v4.z * w3; acc[3][j].w += v4.w * w3;
      }
    }
  };

  // CPER=16 -> 4 batches, modulo-scheduled, fully unrolled (no reg copies).
  LOADB(xA, 0);
  LOADB(xB, 1); COMPB(xA, 0);
  LOADB(xA, 2); COMPB(xB, 1);
  LOADB(xB, 3); COMPB(xA, 2);
  COMPB(xB, 3);

  size_t base = (((size_t)b * NCH + ch) * MM) * NF4;
#pragma unroll
  for (int m = 0; m < MM; ++m)
#pragma unroll
    for (int j = 0; j < 4; ++j) {
      int f = lane + 64 * j;
      if (f < NF4) sPart4[base + (size_t)m * NF4 + f] = acc[m][j];
    }
}

// ---- K2: hid + deterministic block-partial aD = sum_n hid^2 ----
__global__ __launch_bounds__(256) void k_hid2(const float* __restrict__ sPart,
                                              const float* __restrict__ peW,
                                              float* __restrict__ hid4,
                                              float* __restrict__ aDpart) {
  int g = blockIdx.x;            // n-chunk 0..3
  int b = blockIdx.y;
  int t = threadIdx.x;
  int n = g * 256 + t;
  bool valid = n < NN;
  int wv = t >> 6, lane = t & 63;

  float h[MM];
#pragma unroll
  for (int m = 0; m < MM; ++m) {
    float hm = 0.f;
    if (valid) {
      float s = peW[m * NN + n];
#pragma unroll 8
      for (int ch = 0; ch < NCH; ++ch)
        s += sPart[(((size_t)b * NCH + ch) * MM + m) * NN + n];
      hm = 1.f / (1.f + __expf(-s));
    }
    h[m] = hm;
  }
  if (valid) {
    float4 hv = make_float4(h[0], h[1], h[2], h[3]);
    *(float4*)(hid4 + ((size_t)b * NN + n) * 4) = hv;
  }

  __shared__ float red[4][MM];
#pragma unroll
  for (int m = 0; m < MM; ++m) {
    float q = wred(h[m] * h[m]);
    if (lane == 0) red[wv][m] = q;
  }
  __syncthreads();
  if (t < MM)
    aDpart[((size_t)b * 4 + g) * MM + t] = red[0][t] + red[1][t] + red[2][t] + red[3][t];
}

// ---- K3: out[b,c] = sum_m (inv*aX[m] + aP[m]) / (aD[m]+lambda);
//          aD precomputed (no aD FMAs/wreds here); __sinf proven form. ----
__global__ __launch_bounds__(256) void k_out3(const float* __restrict__ x,
                                              const float* __restrict__ hid4,
                                              const float* __restrict__ inv_norm,
                                              const float* __restrict__ aDpart,
                                              float* __restrict__ out) {
  int idx  = blockIdx.x * 4 + (threadIdx.x >> 6);   // (b*C+c)
  int lane = threadIdx.x & 63;
  int b = idx >> 11;
  int c = idx & (CC - 1);
  const float4* row = (const float4*)(x + (size_t)idx * NN);
  const float4* hb  = (const float4*)(hid4 + (size_t)b * NN * 4);
  float di = __expf(-((float)(c & ~1) * (1.0f / CC)) * LOG1E4);
  bool use_sin = !(c & 1);
  float aX0=0,aX1=0,aX2=0,aX3=0, aP0=0,aP1=0,aP2=0,aP3=0;
  for (int f = lane; f < NF4; f += 64) {
    float4 xv = row[f];
    int n = f * 4;
    float4 h0 = hb[n + 0], h1 = hb[n + 1], h2 = hb[n + 2], h3 = hb[n + 3];
    float a0 = (float)(n + 0) * di, a1 = (float)(n + 1) * di;
    float a2 = (float)(n + 2) * di, a3 = (float)(n + 3) * di;
    float p0 = use_sin ? __sinf(a0) : __cosf(a0);
    float p1 = use_sin ? __sinf(a1) : __cosf(a1);
    float p2 = use_sin ? __sinf(a2) : __cosf(a2);
    float p3 = use_sin ? __sinf(a3) : __cosf(a3);
    aX0 += xv.x*h0.x + xv.y*h1.x + xv.z*h2.x + xv.w*h3.x;
    aX1 += xv.x*h0.y + xv.y*h1.y + xv.z*h2.y + xv.w*h3.y;
    aX2 += xv.x*h0.z + xv.y*h1.z + xv.z*h2.z + xv.w*h3.z;
    aX3 += xv.x*h0.w + xv.y*h1.w + xv.z*h2.w + xv.w*h3.w;
    aP0 += p0*h0.x + p1*h1.x + p2*h2.x + p3*h3.x;
    aP1 += p0*h0.y + p1*h1.y + p2*h2.y + p3*h3.y;
    aP2 += p0*h0.z + p1*h1.z + p2*h2.z + p3*h3.z;
    aP3 += p0*h0.w + p1*h1.w + p2*h2.w + p3*h3.w;
  }
  aX0 = wred(aX0); aX1 = wred(aX1); aX2 = wred(aX2); aX3 = wred(aX3);
  aP0 = wred(aP0); aP1 = wred(aP1); aP2 = wred(aP2); aP3 = wred(aP3);
  if (lane == 0) {
    const float* ad = aDpart + (size_t)b * 4 * MM;
    float aD0 = ad[0] + ad[4] + ad[8]  + ad[12];
    float aD1 = ad[1] + ad[5] + ad[9]  + ad[13];
    float aD2 = ad[2] + ad[6] + ad[10] + ad[14];
    float aD3 = ad[3] + ad[7] + ad[11] + ad[15];
    float inv = inv_norm[idx];
    float r = (inv * aX0 + aP0) / (aD0 + LAMBDA_)
            + (inv * aX1 + aP1) / (aD1 + LAMBDA_)
            + (inv * aX2 + aP2) / (aD2 + LAMBDA_)
            + (inv * aX3 + aP3) / (aD3 + LAMBDA_);
    if (isnan(r)) r = 0.f;
    else if (isinf(r)) r = (r > 0.f) ? 3.4028234663852886e38f : -3.4028234663852886e38f;
    out[idx] = r;
  }
}

extern "C" void kernel_launch(void* const* d_in, const int* in_sizes, int n_in,
                              void* d_out, int out_size, void* d_ws, size_t ws_size,
                              hipStream_t stream) {
  const float* x = (const float*)d_in[0];   // (B, C, S, S)
  const float* W = (const float*)d_in[1];   // (M, C, 1)
  float* out = (float*)d_out;               // (B, 1, C)
  float* ws  = (float*)d_ws;

  float* inv_norm = ws;                                   // B*C       = 65536
  float* peW      = inv_norm + (size_t)BB * CC;           // M*N       = 3136
  float* hid4     = peW + (size_t)MM * NN;                // B*N*M     = 401408
  float* aDpart   = hid4 + (size_t)BB * NN * MM;          // B*4*M     = 512
  float* sPart    = aDpart + (size_t)BB * 4 * MM;         // B*NCH*M*N = 12.8M floats

  k_sacc2v2<<<dim3(NCH / 4 + 1, BB), 256, 0, stream>>>(x, W, inv_norm, peW, (float4*)sPart);
  k_hid2<<<dim3(4, BB), 256, 0, stream>>>(sPart, peW, hid4, aDpart);
  k_out3<<<OUT_BLOCKS, 256, 0, stream>>>(x, hid4, inv_norm, aDpart, out);
}

// Round 10
// 235.916 us; speedup vs baseline: 1.9518x; 1.9518x over previous
//
#include <hip/hip_runtime.h>
#include <math.h>

#define BB 32
#define CC 2048
#define NN 784          // 28*28
#define NF4 196         // float4 per (b,c) spatial row
#define MM 4
#define NCH 128         // channel chunks (CPER=16 per wave)
#define CPER (CC / NCH)
#define LAMBDA_ 1e-3f
#define EPS_ 1e-10f
#define LOG1E4 9.210340371976184f
#define OUT_BLOCKS (BB * CC / 4)    // 16384

__device__ __forceinline__ float wred(float v) {
#pragma unroll
  for (int off = 32; off > 0; off >>= 1) v += __shfl_down(v, off, 64);
  return v;
}

// ---- K1: fused norm + partial dot. Wave-private (no LDS/barriers).
//          4 channels per step: 4 interleaved butterflies (4-way ILP on the
//          shfl chain), double-batch ping-pong, fully static indexing.
//          __launch_bounds__(256) ONLY (R4-proven): no bound -> hipcc assumes
//          1024-thr blocks -> 64-VGPR cap -> total spill (R9, 375us);
//          (256,4) -> 64 VGPR spill (R5); (256,2) -> 80 VGPR remat (R6).
//          Need ~228 live VGPRs: only the plain (256) bound allows it. ----
template <int DUMMY>
__global__ __launch_bounds__(256) void k_sacc2v2(const float* __restrict__ x,
                                                 const float* __restrict__ W,
                                                 float* __restrict__ inv_norm,
                                                 float* __restrict__ peW,
                                                 float4* __restrict__ sPart4) {
  int b    = blockIdx.y;
  int wv   = threadIdx.x >> 6;
  int lane = threadIdx.x & 63;

  if (blockIdx.x == NCH / 4) {
    // peW[m,n] = sum_c pe[n,c]*W[m,c]; 25-wide n slice per b.
    const int NPS = (NN + BB - 1) / BB;   // 25
    int n0 = b * NPS, n1 = (n0 + NPS < NN) ? n0 + NPS : NN;
    int m = wv;
    for (int n = n0; n < n1; ++n) {
      float acc = 0.f;
      for (int c = lane; c < CC; c += 64) {
        float di  = __expf(-((float)(c & ~1) * (1.f / CC)) * LOG1E4);
        float arg = (float)n * di;
        float pe  = (c & 1) ? __cosf(arg) : __sinf(arg);
        acc += pe * W[m * CC + c];
      }
      acc = wred(acc);
      if (lane == 0) peW[m * NN + n] = acc;
    }
    return;
  }

  int ch = blockIdx.x * 4 + wv;
  int c0 = ch * CPER;
  const float4* xb = (const float4*)(x + ((size_t)b * CC + c0) * NN);
  const float4 z = make_float4(0.f, 0.f, 0.f, 0.f);

  float4 acc[MM][4];
#pragma unroll
  for (int m = 0; m < MM; ++m)
#pragma unroll
    for (int j = 0; j < 4; ++j) acc[m][j] = z;

  float4 xA[4][4], xB[4][4];   // [channel-in-batch][slot]

  auto LOADB = [&](float4 d[4][4], int bt) {   // load 4 channels of batch bt
#pragma unroll
    for (int k = 0; k < 4; ++k) {
      const float4* p = xb + (size_t)(bt * 4 + k) * NF4 + lane;
      d[k][0] = p[0];
      d[k][1] = p[64];
      d[k][2] = p[128];
      d[k][3] = (lane < (NF4 - 192)) ? p[192] : z;
    }
  };

  auto COMPB = [&](const float4 v[4][4], int bt) {
    int cb = c0 + bt * 4;
    float wl[4][MM];
#pragma unroll
    for (int k = 0; k < 4; ++k)
#pragma unroll
      for (int m = 0; m < MM; ++m) wl[k][m] = W[m * CC + cb + k];
    float sq[4];
#pragma unroll
    for (int k = 0; k < 4; ++k) {
      sq[k] = v[k][0].x*v[k][0].x + v[k][0].y*v[k][0].y + v[k][0].z*v[k][0].z + v[k][0].w*v[k][0].w
            + v[k][1].x*v[k][1].x + v[k][1].y*v[k][1].y + v[k][1].z*v[k][1].z + v[k][1].w*v[k][1].w
            + v[k][2].x*v[k][2].x + v[k][2].y*v[k][2].y + v[k][2].z*v[k][2].z + v[k][2].w*v[k][2].w
            + v[k][3].x*v[k][3].x + v[k][3].y*v[k][3].y + v[k][3].z*v[k][3].z + v[k][3].w*v[k][3].w;
    }
    // interleaved butterflies: 4 independent chains per level
#pragma unroll
    for (int o = 1; o < 64; o <<= 1) {
      sq[0] += __shfl_xor(sq[0], o, 64);
      sq[1] += __shfl_xor(sq[1], o, 64);
      sq[2] += __shfl_xor(sq[2], o, 64);
      sq[3] += __shfl_xor(sq[3], o, 64);
    }
    float inv[4];
#pragma unroll
    for (int k = 0; k < 4; ++k) inv[k] = 1.f / fmaxf(sqrtf(sq[k]), EPS_);
    if (lane == 0) {
#pragma unroll
      for (int k = 0; k < 4; ++k) inv_norm[b * CC + cb + k] = inv[k];
    }
#pragma unroll
    for (int k = 0; k < 4; ++k) {
      float w0 = inv[k] * wl[k][0];
      float w1 = inv[k] * wl[k][1];
      float w2 = inv[k] * wl[k][2];
      float w3 = inv[k] * wl[k][3];
#pragma unroll
      for (int j = 0; j < 4; ++j) {
        float4 v4 = v[k][j];
        acc[0][j].x += v4.x * w0; acc[0][j].y += v4.y * w0; acc[0][j].z += v4.z * w0; acc[0][j].w += v4.w * w0;
        acc[1][j].x += v4.x * w1; acc[1][j].y += v4.y * w1; acc[1][j].z += v4.z * w1; acc[1][j].w += v4.w * w1;
        acc[2][j].x += v4.x * w2; acc[2][j].y += v4.y * w2; acc[2][j].z += v4.z * w2; acc[2][j].w += v4.w * w2;
        acc[3][j].x += v4.x * w3; acc[3][j].y += v4.y * w3; acc[3][j].z += v4.z * w3; acc[3][j].w += v4.w * w3;
      }
    }
  };

  // CPER=16 -> 4 batches, modulo-scheduled, fully unrolled.
  LOADB(xA, 0);
  LOADB(xB, 1); COMPB(xA, 0);
  LOADB(xA, 2); COMPB(xB, 1);
  LOADB(xB, 3); COMPB(xA, 2);
  COMPB(xB, 3);

  size_t base = (((size_t)b * NCH + ch) * MM) * NF4;
#pragma unroll
  for (int m = 0; m < MM; ++m)
#pragma unroll
    for (int j = 0; j < 4; ++j) {
      int f = lane + 64 * j;
      if (f < NF4) sPart4[base + (size_t)m * NF4 + f] = acc[m][j];
    }
}

// ---- K2: hid + deterministic block-partial aD = sum_n hid^2 ----
__global__ __launch_bounds__(256) void k_hid2(const float* __restrict__ sPart,
                                              const float* __restrict__ peW,
                                              float* __restrict__ hid4,
                                              float* __restrict__ aDpart) {
  int g = blockIdx.x;            // n-chunk 0..3
  int b = blockIdx.y;
  int t = threadIdx.x;
  int n = g * 256 + t;
  bool valid = n < NN;
  int wv = t >> 6, lane = t & 63;

  float h[MM];
#pragma unroll
  for (int m = 0; m < MM; ++m) {
    float hm = 0.f;
    if (valid) {
      float s = peW[m * NN + n];
#pragma unroll 8
      for (int ch = 0; ch < NCH; ++ch)
        s += sPart[(((size_t)b * NCH + ch) * MM + m) * NN + n];
      hm = 1.f / (1.f + __expf(-s));
    }
    h[m] = hm;
  }
  if (valid) {
    float4 hv = make_float4(h[0], h[1], h[2], h[3]);
    *(float4*)(hid4 + ((size_t)b * NN + n) * 4) = hv;
  }

  __shared__ float red[4][MM];
#pragma unroll
  for (int m = 0; m < MM; ++m) {
    float q = wred(h[m] * h[m]);
    if (lane == 0) red[wv][m] = q;
  }
  __syncthreads();
  if (t < MM)
    aDpart[((size_t)b * 4 + g) * MM + t] = red[0][t] + red[1][t] + red[2][t] + red[3][t];
}

// ---- K3: out[b,c] = sum_m (inv*aX[m] + aP[m]) / (aD[m]+lambda) ----
__global__ __launch_bounds__(256) void k_out3(const float* __restrict__ x,
                                              const float* __restrict__ hid4,
                                              const float* __restrict__ inv_norm,
                                              const float* __restrict__ aDpart,
                                              float* __restrict__ out) {
  int idx  = blockIdx.x * 4 + (threadIdx.x >> 6);   // (b*C+c)
  int lane = threadIdx.x & 63;
  int b = idx >> 11;
  int c = idx & (CC - 1);
  const float4* row = (const float4*)(x + (size_t)idx * NN);
  const float4* hb  = (const float4*)(hid4 + (size_t)b * NN * 4);
  float di = __expf(-((float)(c & ~1) * (1.0f / CC)) * LOG1E4);
  bool use_sin = !(c & 1);
  float aX0=0,aX1=0,aX2=0,aX3=0, aP0=0,aP1=0,aP2=0,aP3=0;
  for (int f = lane; f < NF4; f += 64) {
    float4 xv = row[f];
    int n = f * 4;
    float4 h0 = hb[n + 0], h1 = hb[n + 1], h2 = hb[n + 2], h3 = hb[n + 3];
    float a0 = (float)(n + 0) * di, a1 = (float)(n + 1) * di;
    float a2 = (float)(n + 2) * di, a3 = (float)(n + 3) * di;
    float p0 = use_sin ? __sinf(a0) : __cosf(a0);
    float p1 = use_sin ? __sinf(a1) : __cosf(a1);
    float p2 = use_sin ? __sinf(a2) : __cosf(a2);
    float p3 = use_sin ? __sinf(a3) : __cosf(a3);
    aX0 += xv.x*h0.x + xv.y*h1.x + xv.z*h2.x + xv.w*h3.x;
    aX1 += xv.x*h0.y + xv.y*h1.y + xv.z*h2.y + xv.w*h3.y;
    aX2 += xv.x*h0.z + xv.y*h1.z + xv.z*h2.z + xv.w*h3.z;
    aX3 += xv.x*h0.w + xv.y*h1.w + xv.z*h2.w + xv.w*h3.w;
    aP0 += p0*h0.x + p1*h1.x + p2*h2.x + p3*h3.x;
    aP1 += p0*h0.y + p1*h1.y + p2*h2.y + p3*h3.y;
    aP2 += p0*h0.z + p1*h1.z + p2*h2.z + p3*h3.z;
    aP3 += p0*h0.w + p1*h1.w + p2*h2.w + p3*h3.w;
  }
  aX0 = wred(aX0); aX1 = wred(aX1); aX2 = wred(aX2); aX3 = wred(aX3);
  aP0 = wred(aP0); aP1 = wred(aP1); aP2 = wred(aP2); aP3 = wred(aP3);
  if (lane == 0) {
    const float* ad = aDpart + (size_t)b * 4 * MM;
    float aD0 = ad[0] + ad[4] + ad[8]  + ad[12];
    float aD1 = ad[1] + ad[5] + ad[9]  + ad[13];
    float aD2 = ad[2] + ad[6] + ad[10] + ad[14];
    float aD3 = ad[3] + ad[7] + ad[11] + ad[15];
    float inv = inv_norm[idx];
    float r = (inv * aX0 + aP0) / (aD0 + LAMBDA_)
            + (inv * aX1 + aP1) / (aD1 + LAMBDA_)
            + (inv * aX2 + aP2) / (aD2 + LAMBDA_)
            + (inv * aX3 + aP3) / (aD3 + LAMBDA_);
    if (isnan(r)) r = 0.f;
    else if (isinf(r)) r = (r > 0.f) ? 3.4028234663852886e38f : -3.4028234663852886e38f;
    out[idx] = r;
  }
}

extern "C" void kernel_launch(void* const* d_in, const int* in_sizes, int n_in,
                              void* d_out, int out_size, void* d_ws, size_t ws_size,
                              hipStream_t stream) {
  const float* x = (const float*)d_in[0];   // (B, C, S, S)
  const float* W = (const float*)d_in[1];   // (M, C, 1)
  float* out = (float*)d_out;               // (B, 1, C)
  float* ws  = (float*)d_ws;

  float* inv_norm = ws;                                   // B*C       = 65536
  float* peW      = inv_norm + (size_t)BB * CC;           // M*N       = 3136
  float* hid4     = peW + (size_t)MM * NN;                // B*N*M     = 401408
  float* aDpart   = hid4 + (size_t)BB * NN * MM;          // B*4*M     = 512
  float* sPart    = aDpart + (size_t)BB * 4 * MM;         // B*NCH*M*N = 12.8M floats

  k_sacc2v2<0><<<dim3(NCH / 4 + 1, BB), 256, 0, stream>>>(x, W, inv_norm, peW, (float4*)sPart);
  k_hid2<<<dim3(4, BB), 256, 0, stream>>>(sPart, peW, hid4, aDpart);
  k_out3<<<OUT_BLOCKS, 256, 0, stream>>>(x, hid4, inv_norm, aDpart, out);
}

// Round 11
// 166.038 us; speedup vs baseline: 2.7733x; 1.4209x over previous
//
#include <hip/hip_runtime.h>
#include <math.h>

#define BB 32
#define CC 2048
#define NN 784          // 28*28
#define NF4 196         // float4 per (b,c) spatial row
#define MM 4
#define NCH 64          // channel chunks for the dot pass
#define CPER (CC / NCH) // 32 channels per block
#define LAMBDA_ 1e-3f
#define EPS_ 1e-10f
#define LOG1E4 9.210340371976184f
#define NORMB (BB * CC / 4)         // 4096 norm blocks (4 row-waves each)
#define OUT_BLOCKS (BB * CC / 4)    // 16384

__device__ __forceinline__ float wred(float v) {
#pragma unroll
  for (int off = 32; off > 0; off >>= 1) v += __shfl_down(v, off, 64);
  return v;
}

// ---- K1: wave-per-row norm -> inv_norm + pre-scaled weights Ws[b,m,c];
//          peW side-blocks (bid >= NORMB). Lean (no LDS/barriers). ----
__global__ __launch_bounds__(256) void k_norm_w(const float* __restrict__ x,
                                                const float* __restrict__ W,
                                                float* __restrict__ inv_norm,
                                                float* __restrict__ Ws,
                                                float* __restrict__ peW) {
  int bid  = blockIdx.x;
  int wv   = threadIdx.x >> 6;
  int lane = threadIdx.x & 63;

  if (bid >= NORMB) {
    int n = bid - NORMB;
    int m = wv;
    float acc = 0.f;
    for (int c = lane; c < CC; c += 64) {
      float di  = __expf(-((float)(c & ~1) * (1.f / CC)) * LOG1E4);
      float arg = (float)n * di;
      float pe  = (c & 1) ? __cosf(arg) : __sinf(arg);
      acc += pe * W[m * CC + c];
    }
    acc = wred(acc);
    if (lane == 0) peW[m * NN + n] = acc;
    return;
  }

  int idx = bid * 4 + wv;            // (b*C+c)
  int b = idx >> 11;
  int c = idx & (CC - 1);
  const float4* row = (const float4*)(x + (size_t)idx * NN);
  float4 v0 = row[lane];
  float4 v1 = row[lane + 64];
  float4 v2 = row[lane + 128];
  float4 v3 = (lane < (NF4 - 192)) ? row[lane + 192] : make_float4(0.f, 0.f, 0.f, 0.f);
  float ss = v0.x*v0.x + v0.y*v0.y + v0.z*v0.z + v0.w*v0.w
           + v1.x*v1.x + v1.y*v1.y + v1.z*v1.z + v1.w*v1.w
           + v2.x*v2.x + v2.y*v2.y + v2.z*v2.z + v2.w*v2.w
           + v3.x*v3.x + v3.y*v3.y + v3.z*v3.z + v3.w*v3.w;
  ss = wred(ss);
  if (lane == 0) {
    float inv = 1.f / fmaxf(sqrtf(ss), EPS_);
    inv_norm[idx] = inv;
#pragma unroll
    for (int m = 0; m < MM; ++m)
      Ws[((size_t)b * MM + m) * CC + c] = W[m * CC + c] * inv;
  }
}

// ---- K2: partial dot, thread-per-pixel-float4, serial channels.
//          LEAN: no shfl/LDS/barriers; unroll 4 (live ~50 VGPR); pinned to
//          the 64-VGPR occupancy bin (8 waves/SIMD) via launch_bounds(256,8).
//          NCH=64 -> 2048 blocks = 8 blocks/CU resident. ----
__global__ __launch_bounds__(256, 8) void k_sacc5(const float* __restrict__ x,
                                                  const float* __restrict__ Ws,
                                                  float4* __restrict__ sPart4) {
  int t  = threadIdx.x;          // float4 index within row
  int ch = blockIdx.x;
  int b  = blockIdx.y;
  if (t >= NF4) return;
  int c0 = ch * CPER;
  const float4* xb = (const float4*)(x + ((size_t)b * CC + c0) * NN) + t;
  const float* wb  = Ws + (size_t)b * MM * CC + c0;   // wave-uniform -> s_load

  float4 a0{0,0,0,0}, a1{0,0,0,0}, a2{0,0,0,0}, a3{0,0,0,0};

  for (int i = 0; i < CPER; i += 4) {
    float4 xv[4];
#pragma unroll
    for (int u = 0; u < 4; ++u) xv[u] = xb[(size_t)(i + u) * NF4];
#pragma unroll
    for (int u = 0; u < 4; ++u) {
      int c = i + u;
      float w0 = wb[0 * CC + c];
      float w1 = wb[1 * CC + c];
      float w2 = wb[2 * CC + c];
      float w3 = wb[3 * CC + c];
      float4 v = xv[u];
      a0.x += v.x * w0; a0.y += v.y * w0; a0.z += v.z * w0; a0.w += v.w * w0;
      a1.x += v.x * w1; a1.y += v.y * w1; a1.z += v.z * w1; a1.w += v.w * w1;
      a2.x += v.x * w2; a2.y += v.y * w2; a2.z += v.z * w2; a2.w += v.w * w2;
      a3.x += v.x * w3; a3.y += v.y * w3; a3.z += v.z * w3; a3.w += v.w * w3;
    }
  }
  size_t base = (((size_t)b * NCH + ch) * MM) * NF4 + t;
  sPart4[base + 0 * NF4] = a0;
  sPart4[base + 1 * NF4] = a1;
  sPart4[base + 2 * NF4] = a2;
  sPart4[base + 3 * NF4] = a3;
}

// ---- K3: hid + deterministic block-partial aD = sum_n hid^2 ----
__global__ __launch_bounds__(256) void k_hid2(const float* __restrict__ sPart,
                                              const float* __restrict__ peW,
                                              float* __restrict__ hid4,
                                              float* __restrict__ aDpart) {
  int g = blockIdx.x;            // n-chunk 0..3
  int b = blockIdx.y;
  int t = threadIdx.x;
  int n = g * 256 + t;
  bool valid = n < NN;
  int wv = t >> 6, lane = t & 63;

  float h[MM];
#pragma unroll
  for (int m = 0; m < MM; ++m) {
    float hm = 0.f;
    if (valid) {
      float s = peW[m * NN + n];
#pragma unroll 8
      for (int ch = 0; ch < NCH; ++ch)
        s += sPart[(((size_t)b * NCH + ch) * MM + m) * NN + n];
      hm = 1.f / (1.f + __expf(-s));
    }
    h[m] = hm;
  }
  if (valid) {
    float4 hv = make_float4(h[0], h[1], h[2], h[3]);
    *(float4*)(hid4 + ((size_t)b * NN + n) * 4) = hv;
  }

  __shared__ float red[4][MM];
#pragma unroll
  for (int m = 0; m < MM; ++m) {
    float q = wred(h[m] * h[m]);
    if (lane == 0) red[wv][m] = q;
  }
  __syncthreads();
  if (t < MM)
    aDpart[((size_t)b * 4 + g) * MM + t] = red[0][t] + red[1][t] + red[2][t] + red[3][t];
}

// ---- K4: out[b,c] = sum_m (inv*aX[m] + aP[m]) / (aD[m]+lambda) ----
__global__ __launch_bounds__(256) void k_out3(const float* __restrict__ x,
                                              const float* __restrict__ hid4,
                                              const float* __restrict__ inv_norm,
                                              const float* __restrict__ aDpart,
                                              float* __restrict__ out) {
  int idx  = blockIdx.x * 4 + (threadIdx.x >> 6);   // (b*C+c)
  int lane = threadIdx.x & 63;
  int b = idx >> 11;
  int c = idx & (CC - 1);
  const float4* row = (const float4*)(x + (size_t)idx * NN);
  const float4* hb  = (const float4*)(hid4 + (size_t)b * NN * 4);
  float di = __expf(-((float)(c & ~1) * (1.0f / CC)) * LOG1E4);
  bool use_sin = !(c & 1);
  float aX0=0,aX1=0,aX2=0,aX3=0, aP0=0,aP1=0,aP2=0,aP3=0;
  for (int f = lane; f < NF4; f += 64) {
    float4 xv = row[f];
    int n = f * 4;
    float4 h0 = hb[n + 0], h1 = hb[n + 1], h2 = hb[n + 2], h3 = hb[n + 3];
    float a0 = (float)(n + 0) * di, a1 = (float)(n + 1) * di;
    float a2 = (float)(n + 2) * di, a3 = (float)(n + 3) * di;
    float p0 = use_sin ? __sinf(a0) : __cosf(a0);
    float p1 = use_sin ? __sinf(a1) : __cosf(a1);
    float p2 = use_sin ? __sinf(a2) : __cosf(a2);
    float p3 = use_sin ? __sinf(a3) : __cosf(a3);
    aX0 += xv.x*h0.x + xv.y*h1.x + xv.z*h2.x + xv.w*h3.x;
    aX1 += xv.x*h0.y + xv.y*h1.y + xv.z*h2.y + xv.w*h3.y;
    aX2 += xv.x*h0.z + xv.y*h1.z + xv.z*h2.z + xv.w*h3.z;
    aX3 += xv.x*h0.w + xv.y*h1.w + xv.z*h2.w + xv.w*h3.w;
    aP0 += p0*h0.x + p1*h1.x + p2*h2.x + p3*h3.x;
    aP1 += p0*h0.y + p1*h1.y + p2*h2.y + p3*h3.y;
    aP2 += p0*h0.z + p1*h1.z + p2*h2.z + p3*h3.z;
    aP3 += p0*h0.w + p1*h1.w + p2*h2.w + p3*h3.w;
  }
  aX0 = wred(aX0); aX1 = wred(aX1); aX2 = wred(aX2); aX3 = wred(aX3);
  aP0 = wred(aP0); aP1 = wred(aP1); aP2 = wred(aP2); aP3 = wred(aP3);
  if (lane == 0) {
    const float* ad = aDpart + (size_t)b * 4 * MM;
    float aD0 = ad[0] + ad[4] + ad[8]  + ad[12];
    float aD1 = ad[1] + ad[5] + ad[9]  + ad[13];
    float aD2 = ad[2] + ad[6] + ad[10] + ad[14];
    float aD3 = ad[3] + ad[7] + ad[11] + ad[15];
    float inv = inv_norm[idx];
    float r = (inv * aX0 + aP0) / (aD0 + LAMBDA_)
            + (inv * aX1 + aP1) / (aD1 + LAMBDA_)
            + (inv * aX2 + aP2) / (aD2 + LAMBDA_)
            + (inv * aX3 + aP3) / (aD3 + LAMBDA_);
    if (isnan(r)) r = 0.f;
    else if (isinf(r)) r = (r > 0.f) ? 3.4028234663852886e38f : -3.4028234663852886e38f;
    out[idx] = r;
  }
}

extern "C" void kernel_launch(void* const* d_in, const int* in_sizes, int n_in,
                              void* d_out, int out_size, void* d_ws, size_t ws_size,
                              hipStream_t stream) {
  const float* x = (const float*)d_in[0];   // (B, C, S, S)
  const float* W = (const float*)d_in[1];   // (M, C, 1)
  float* out = (float*)d_out;               // (B, 1, C)
  float* ws  = (float*)d_ws;

  float* inv_norm = ws;                                   // B*C       = 65536
  float* peW      = inv_norm + (size_t)BB * CC;           // M*N       = 3136
  float* hid4     = peW + (size_t)MM * NN;                // B*N*M     = 401408
  float* Ws       = hid4 + (size_t)BB * NN * MM;          // B*M*C     = 262144
  float* aDpart   = Ws + (size_t)BB * MM * CC;            // B*4*M     = 512
  float* sPart    = aDpart + (size_t)BB * 4 * MM;         // B*NCH*M*N = 6.42M floats

  k_norm_w<<<NORMB + NN, 256, 0, stream>>>(x, W, inv_norm, Ws, peW);
  k_sacc5<<<dim3(NCH, BB), 256, 0, stream>>>(x, Ws, (float4*)sPart);
  k_hid2<<<dim3(4, BB), 256, 0, stream>>>(sPart, peW, hid4, aDpart);
  k_out3<<<OUT_BLOCKS, 256, 0, stream>>>(x, hid4, inv_norm, aDpart, out);
}

// Round 12
// 154.986 us; speedup vs baseline: 2.9710x; 1.0713x over previous
//
#include <hip/hip_runtime.h>
#include <hip/hip_fp16.h>
#include <math.h>

#define BB 32
#define CC 2048
#define NN 784          // 28*28
#define NH4 196         // half4 (8B) chunks per (b,c) row
#define MM 4
#define NCH 32          // channel chunks for the dot pass
#define CPER (CC / NCH) // 64 channels per block
#define LAMBDA_ 1e-3f
#define EPS_ 1e-10f
#define LOG1E4 9.210340371976184f
#define NORMB (BB * CC / 4)         // 16384 norm blocks (4 row-waves each)
#define OUT_BLOCKS (BB * CC / 4)

struct alignas(8) half4_t { __half2 lo, hi; };

__device__ __forceinline__ float wred(float v) {
#pragma unroll
  for (int off = 32; off > 0; off >>= 1) v += __shfl_down(v, off, 64);
  return v;
}

// ---- K1: wave-per-row norm; writes x-hat (normalized x) as fp16.
//          peW side-blocks (bid >= NORMB). No LDS/barriers, lean VGPR. ----
__global__ __launch_bounds__(256) void k_norm_h(const float* __restrict__ x,
                                                const float* __restrict__ W,
                                                half4_t* __restrict__ xh,
                                                float* __restrict__ peW) {
  int bid  = blockIdx.x;
  int wv   = threadIdx.x >> 6;
  int lane = threadIdx.x & 63;

  if (bid >= NORMB) {
    int n = bid - NORMB;
    int m = wv;
    float acc = 0.f;
    for (int c = lane; c < CC; c += 64) {
      float di  = __expf(-((float)(c & ~1) * (1.f / CC)) * LOG1E4);
      float arg = (float)n * di;
      float pe  = (c & 1) ? __cosf(arg) : __sinf(arg);
      acc += pe * W[m * CC + c];
    }
    acc = wred(acc);
    if (lane == 0) peW[m * NN + n] = acc;
    return;
  }

  int idx = bid * 4 + wv;            // (b*C+c)
  const float4* row = (const float4*)(x + (size_t)idx * NN);
  float4 v0 = row[lane];
  float4 v1 = row[lane + 64];
  float4 v2 = row[lane + 128];
  float4 v3 = (lane < 4) ? row[lane + 192] : make_float4(0.f, 0.f, 0.f, 0.f);
  float ss = v0.x*v0.x + v0.y*v0.y + v0.z*v0.z + v0.w*v0.w
           + v1.x*v1.x + v1.y*v1.y + v1.z*v1.z + v1.w*v1.w
           + v2.x*v2.x + v2.y*v2.y + v2.z*v2.z + v2.w*v2.w
           + v3.x*v3.x + v3.y*v3.y + v3.z*v3.z + v3.w*v3.w;
#pragma unroll
  for (int o = 1; o < 64; o <<= 1) ss += __shfl_xor(ss, o, 64);   // all lanes
  float inv = 1.f / fmaxf(sqrtf(ss), EPS_);

  half4_t* orow = xh + (size_t)idx * NH4;
  half4_t p;
  p.lo = __floats2half2_rn(v0.x * inv, v0.y * inv);
  p.hi = __floats2half2_rn(v0.z * inv, v0.w * inv);
  orow[lane] = p;
  p.lo = __floats2half2_rn(v1.x * inv, v1.y * inv);
  p.hi = __floats2half2_rn(v1.z * inv, v1.w * inv);
  orow[lane + 64] = p;
  p.lo = __floats2half2_rn(v2.x * inv, v2.y * inv);
  p.hi = __floats2half2_rn(v2.z * inv, v2.w * inv);
  orow[lane + 128] = p;
  if (lane < 4) {
    p.lo = __floats2half2_rn(v3.x * inv, v3.y * inv);
    p.hi = __floats2half2_rn(v3.z * inv, v3.w * inv);
    orow[lane + 192] = p;
  }
}

// ---- K2: partial dot from fp16 x-hat; raw W scalar loads (no Ws).
//          Thread-per-4-pixels, serial channels, unroll 8, lean. ----
__global__ __launch_bounds__(256) void k_sacc6(const half4_t* __restrict__ xh,
                                               const float* __restrict__ W,
                                               float4* __restrict__ sPart4) {
  int t  = threadIdx.x;          // half4 index within row
  int ch = blockIdx.x;
  int b  = blockIdx.y;
  if (t >= NH4) return;
  int c0 = ch * CPER;
  const half4_t* xb = xh + ((size_t)b * CC + c0) * NH4 + t;

  float4 a0{0,0,0,0}, a1{0,0,0,0}, a2{0,0,0,0}, a3{0,0,0,0};

  for (int i = 0; i < CPER; i += 8) {
    half4_t xv[8];
#pragma unroll
    for (int u = 0; u < 8; ++u) xv[u] = xb[(size_t)(i + u) * NH4];
#pragma unroll
    for (int u = 0; u < 8; ++u) {
      int c = c0 + i + u;
      float w0 = W[0 * CC + c];
      float w1 = W[1 * CC + c];
      float w2 = W[2 * CC + c];
      float w3 = W[3 * CC + c];
      float2 lo = __half22float2(xv[u].lo);
      float2 hi = __half22float2(xv[u].hi);
      a0.x += lo.x * w0; a0.y += lo.y * w0; a0.z += hi.x * w0; a0.w += hi.y * w0;
      a1.x += lo.x * w1; a1.y += lo.y * w1; a1.z += hi.x * w1; a1.w += hi.y * w1;
      a2.x += lo.x * w2; a2.y += lo.y * w2; a2.z += hi.x * w2; a2.w += hi.y * w2;
      a3.x += lo.x * w3; a3.y += lo.y * w3; a3.z += hi.x * w3; a3.w += hi.y * w3;
    }
  }
  size_t base = (((size_t)b * NCH + ch) * MM) * NH4 + t;
  sPart4[base + 0 * NH4] = a0;
  sPart4[base + 1 * NH4] = a1;
  sPart4[base + 2 * NH4] = a2;
  sPart4[base + 3 * NH4] = a3;
}

// ---- K3: hid + deterministic block-partial aD = sum_n hid^2 ----
__global__ __launch_bounds__(256) void k_hid2(const float* __restrict__ sPart,
                                              const float* __restrict__ peW,
                                              float* __restrict__ hid4,
                                              float* __restrict__ aDpart) {
  int g = blockIdx.x;            // n-chunk 0..3
  int b = blockIdx.y;
  int t = threadIdx.x;
  int n = g * 256 + t;
  bool valid = n < NN;
  int wv = t >> 6, lane = t & 63;

  float h[MM];
#pragma unroll
  for (int m = 0; m < MM; ++m) {
    float hm = 0.f;
    if (valid) {
      float s = peW[m * NN + n];
#pragma unroll 8
      for (int ch = 0; ch < NCH; ++ch)
        s += sPart[(((size_t)b * NCH + ch) * MM + m) * NN + n];
      hm = 1.f / (1.f + __expf(-s));
    }
    h[m] = hm;
  }
  if (valid) {
    float4 hv = make_float4(h[0], h[1], h[2], h[3]);
    *(float4*)(hid4 + ((size_t)b * NN + n) * 4) = hv;
  }

  __shared__ float red[4][MM];
#pragma unroll
  for (int m = 0; m < MM; ++m) {
    float q = wred(h[m] * h[m]);
    if (lane == 0) red[wv][m] = q;
  }
  __syncthreads();
  if (t < MM)
    aDpart[((size_t)b * 4 + g) * MM + t] = red[0][t] + red[1][t] + red[2][t] + red[3][t];
}

// ---- K4: out[b,c] = sum_m (aX[m] + aP[m]) / (aD[m]+lambda);
//          aX from fp16 x-hat directly (no inv multiply). ----
__global__ __launch_bounds__(256) void k_out4(const half4_t* __restrict__ xh,
                                              const float* __restrict__ hid4,
                                              const float* __restrict__ aDpart,
                                              float* __restrict__ out) {
  int idx  = blockIdx.x * 4 + (threadIdx.x >> 6);   // (b*C+c)
  int lane = threadIdx.x & 63;
  int b = idx >> 11;
  int c = idx & (CC - 1);
  const half4_t* row = xh + (size_t)idx * NH4;
  const float4* hb   = (const float4*)(hid4 + (size_t)b * NN * 4);
  float di = __expf(-((float)(c & ~1) * (1.0f / CC)) * LOG1E4);
  bool use_sin = !(c & 1);
  float aX0=0,aX1=0,aX2=0,aX3=0, aP0=0,aP1=0,aP2=0,aP3=0;
  for (int f = lane; f < NH4; f += 64) {
    half4_t xv = row[f];
    float2 lo = __half22float2(xv.lo);
    float2 hi = __half22float2(xv.hi);
    int n = f * 4;
    float4 h0 = hb[n + 0], h1 = hb[n + 1], h2 = hb[n + 2], h3 = hb[n + 3];
    float a0 = (float)(n + 0) * di, a1 = (float)(n + 1) * di;
    float a2 = (float)(n + 2) * di, a3 = (float)(n + 3) * di;
    float p0 = use_sin ? __sinf(a0) : __cosf(a0);
    float p1 = use_sin ? __sinf(a1) : __cosf(a1);
    float p2 = use_sin ? __sinf(a2) : __cosf(a2);
    float p3 = use_sin ? __sinf(a3) : __cosf(a3);
    aX0 += lo.x*h0.x + lo.y*h1.x + hi.x*h2.x + hi.y*h3.x;
    aX1 += lo.x*h0.y + lo.y*h1.y + hi.x*h2.y + hi.y*h3.y;
    aX2 += lo.x*h0.z + lo.y*h1.z + hi.x*h2.z + hi.y*h3.z;
    aX3 += lo.x*h0.w + lo.y*h1.w + hi.x*h2.w + hi.y*h3.w;
    aP0 += p0*h0.x + p1*h1.x + p2*h2.x + p3*h3.x;
    aP1 += p0*h0.y + p1*h1.y + p2*h2.y + p3*h3.y;
    aP2 += p0*h0.z + p1*h1.z + p2*h2.z + p3*h3.z;
    aP3 += p0*h0.w + p1*h1.w + p2*h2.w + p3*h3.w;
  }
  aX0 = wred(aX0); aX1 = wred(aX1); aX2 = wred(aX2); aX3 = wred(aX3);
  aP0 = wred(aP0); aP1 = wred(aP1); aP2 = wred(aP2); aP3 = wred(aP3);
  if (lane == 0) {
    const float* ad = aDpart + (size_t)b * 4 * MM;
    float aD0 = ad[0] + ad[4] + ad[8]  + ad[12];
    float aD1 = ad[1] + ad[5] + ad[9]  + ad[13];
    float aD2 = ad[2] + ad[6] + ad[10] + ad[14];
    float aD3 = ad[3] + ad[7] + ad[11] + ad[15];
    float r = (aX0 + aP0) / (aD0 + LAMBDA_)
            + (aX1 + aP1) / (aD1 + LAMBDA_)
            + (aX2 + aP2) / (aD2 + LAMBDA_)
            + (aX3 + aP3) / (aD3 + LAMBDA_);
    if (isnan(r)) r = 0.f;
    else if (isinf(r)) r = (r > 0.f) ? 3.4028234663852886e38f : -3.4028234663852886e38f;
    out[idx] = r;
  }
}

extern "C" void kernel_launch(void* const* d_in, const int* in_sizes, int n_in,
                              void* d_out, int out_size, void* d_ws, size_t ws_size,
                              hipStream_t stream) {
  const float* x = (const float*)d_in[0];   // (B, C, S, S)
  const float* W = (const float*)d_in[1];   // (M, C, 1)
  float* out = (float*)d_out;               // (B, 1, C)
  float* ws  = (float*)d_ws;

  float* peW    = ws;                                     // M*N       = 3136
  float* hid4   = peW + (size_t)MM * NN;                  // B*N*M     = 401408
  float* aDpart = hid4 + (size_t)BB * NN * MM;            // B*4*M     = 512
  float* sPart  = aDpart + (size_t)BB * 4 * MM;           // B*NCH*M*N = 3.21M floats
  half4_t* xh   = (half4_t*)(sPart + (size_t)BB * NCH * MM * NN);  // B*C*N halves

  k_norm_h<<<NORMB + NN, 256, 0, stream>>>(x, W, xh, peW);
  k_sacc6<<<dim3(NCH, BB), 256, 0, stream>>>(xh, W, (float4*)sPart);
  k_hid2<<<dim3(4, BB), 256, 0, stream>>>(sPart, peW, hid4, aDpart);
  k_out4<<<OUT_BLOCKS, 256, 0, stream>>>(xh, hid4, aDpart, out);
}